// Round 2
// baseline (3745.705 us; speedup 1.0000x reference)
//
#include <hip/hip_runtime.h>
#include <math.h>

#define NSRC 32768
#define NTOT 65536
#define NDST 32768
#define DH   256

__device__ __forceinline__ float wave_reduce(float v) {
#pragma unroll
  for (int off = 32; off > 0; off >>= 1) v += __shfl_xor(v, off, 64);
  return v;
}

// ---------------- GEMM: m[65536,256] = feat[65536,256] @ W[256,256] (f32) ----
// BM=64, BN=256 (full width), BK=16. 256 threads; thread tile 4 rows x 16 cols.
__global__ __launch_bounds__(256) void k_gemm(const float* __restrict__ A,
                                              const float* __restrict__ B,
                                              float* __restrict__ C) {
  __shared__ float As[16][68];    // [k][m], padded to kill bank conflicts
  __shared__ float Bs[16][260];   // [k][n]
  const int t  = threadIdx.x;
  const int bm = blockIdx.x * 64;
  const int tx = t & 15, ty = t >> 4;

  float acc[4][16];
#pragma unroll
  for (int i = 0; i < 4; ++i)
#pragma unroll
    for (int j = 0; j < 16; ++j) acc[i][j] = 0.f;

  const int arow = t >> 2;          // 0..63
  const int akq  = (t & 3) << 2;    // 0,4,8,12
  const int bk   = t >> 4;          // 0..15
  const int bn0  = (t & 15) << 4;   // 0..240

  for (int k0 = 0; k0 < 256; k0 += 16) {
    float4 av  = *(const float4*)(A + (size_t)(bm + arow) * 256 + k0 + akq);
    float4 bv0 = *(const float4*)(B + (size_t)(k0 + bk) * 256 + bn0);
    float4 bv1 = *(const float4*)(B + (size_t)(k0 + bk) * 256 + bn0 + 4);
    float4 bv2 = *(const float4*)(B + (size_t)(k0 + bk) * 256 + bn0 + 8);
    float4 bv3 = *(const float4*)(B + (size_t)(k0 + bk) * 256 + bn0 + 12);
    __syncthreads();
    As[akq + 0][arow] = av.x; As[akq + 1][arow] = av.y;
    As[akq + 2][arow] = av.z; As[akq + 3][arow] = av.w;
    *(float4*)&Bs[bk][bn0]      = bv0;
    *(float4*)&Bs[bk][bn0 + 4]  = bv1;
    *(float4*)&Bs[bk][bn0 + 8]  = bv2;
    *(float4*)&Bs[bk][bn0 + 12] = bv3;
    __syncthreads();
#pragma unroll
    for (int kk = 0; kk < 16; ++kk) {
      float4 a4 = *(const float4*)&As[kk][ty << 2];
      float ar[4] = {a4.x, a4.y, a4.z, a4.w};
#pragma unroll
      for (int q = 0; q < 4; ++q) {
        float4 b4 = *(const float4*)&Bs[kk][(tx << 4) + (q << 2)];
        float br[4] = {b4.x, b4.y, b4.z, b4.w};
#pragma unroll
        for (int i = 0; i < 4; ++i)
#pragma unroll
          for (int j = 0; j < 4; ++j)
            acc[i][(q << 2) + j] = fmaf(ar[i], br[j], acc[i][(q << 2) + j]);
      }
    }
  }
#pragma unroll
  for (int i = 0; i < 4; ++i)
#pragma unroll
    for (int q = 0; q < 4; ++q) {
      float4 o = {acc[i][4 * q], acc[i][4 * q + 1], acc[i][4 * q + 2], acc[i][4 * q + 3]};
      *(float4*)(C + (size_t)(bm + (ty << 2) + i) * 256 + (tx << 4) + (q << 2)) = o;
    }
}

// ---------------- edge scatter: agg[dst] += m[src]; deg[dst] += 1 -----------
__global__ __launch_bounds__(256) void k_scatter(const float* __restrict__ m,
                                                 const int* __restrict__ src,
                                                 const int* __restrict__ dst,
                                                 float* __restrict__ agg,
                                                 float* __restrict__ deg,
                                                 int nE) {
  const int e = blockIdx.x * 4 + (threadIdx.x >> 6);
  if (e >= nE) return;
  const int lane = threadIdx.x & 63;
  const int s = src[e], d = dst[e];
  float4 v = *(const float4*)(m + (size_t)s * DH + lane * 4);
  float* o = agg + (size_t)d * DH + lane * 4;
  atomicAdd(o + 0, v.x);
  atomicAdd(o + 1, v.y);
  atomicAdd(o + 2, v.z);
  atomicAdd(o + 3, v.w);
  if (lane == 0) atomicAdd(deg + d, 1.0f);
}

// ---------------- h = PReLU((agg+m)/(deg+1) + b); out; normalize in place ---
template <bool IS_POS>
__global__ __launch_bounds__(256) void k_hnorm(const float* __restrict__ m,
                                               float* __restrict__ agg,
                                               const float* __restrict__ deg,
                                               const float* __restrict__ b,
                                               const float* __restrict__ pa,
                                               float* __restrict__ hout) {
  const int v = blockIdx.x;
  const int t = threadIdx.x;
  const size_t base = (size_t)v * DH;
  const float dg = deg[v] + 1.0f;  // + self-loop
  float hv = (agg[base + t] + m[base + t]) / dg + b[t];
  const float alpha = pa[0];
  hv = hv >= 0.f ? hv : alpha * hv;
  if (IS_POS && v >= NSRC) hout[(size_t)(v - NSRC) * DH + t] = hv;
  float ss = wave_reduce(hv * hv);
  __shared__ float wsum[4];
  __shared__ float nrm;
  const int lane = t & 63, w = t >> 6;
  if (lane == 0) wsum[w] = ss;
  __syncthreads();
  if (t == 0) nrm = fmaxf(sqrtf(wsum[0] + wsum[1] + wsum[2] + wsum[3]), 1e-8f);
  __syncthreads();
  agg[base + t] = hv / nrm;  // normalized view, in place
}

// ---------------- pos_loss + seed self-loop terms of both neg halves --------
__global__ __launch_bounds__(256) void k_posloss(const float* __restrict__ hpn,
                                                 const float* __restrict__ hnn,
                                                 float* __restrict__ sims) {
  const int i = blockIdx.x * 4 + (threadIdx.x >> 6);
  const int lane = threadIdx.x & 63;
  const size_t base = (size_t)(NSRC + i) * DH + lane * 4;
  float4 x = *(const float4*)(hpn + base);
  float4 y = *(const float4*)(hnn + base);
  float p = wave_reduce(x.x * y.x + x.y * y.y + x.z * y.z + x.w * y.w);
  if (lane == 0) {
    sims[i] = p;              // pos_loss
    sims[NDST + i] = p;       // self-loop term of neg1
    sims[2 * NDST + i] = p;   // self-loop term of neg2
  }
}

// ---------------- per-edge cosine scatter: out[d-NSRC] += dot(anc[d],nei[s])-
__global__ __launch_bounds__(256) void k_edgecos(const float* __restrict__ anc,
                                                 const float* __restrict__ nei,
                                                 const int* __restrict__ src,
                                                 const int* __restrict__ dst,
                                                 float* __restrict__ out,
                                                 int nE) {
  const int e = blockIdx.x * 4 + (threadIdx.x >> 6);
  if (e >= nE) return;
  const int lane = threadIdx.x & 63;
  const int s = src[e], d = dst[e];
  float4 x = *(const float4*)(anc + (size_t)d * DH + lane * 4);
  float4 y = *(const float4*)(nei + (size_t)s * DH + lane * 4);
  float p = wave_reduce(x.x * y.x + x.y * y.y + x.z * y.z + x.w * y.w);
  if (lane == 0) atomicAdd(out + (d - NSRC), p);
}

// ---------------- final log-sum-exp reduce ----------------------------------
__global__ __launch_bounds__(256) void k_reduce(const float* __restrict__ sims,
                                                float* __restrict__ red) {
  const int i = blockIdx.x * 256 + threadIdx.x;  // 3*NDST = 384*256 exactly
  const float v = sims[i];
  float e = expf(v);
  float p = (i < NDST) ? v : 0.f;
  e = wave_reduce(e);
  p = wave_reduce(p);
  __shared__ float se[4], sp[4];
  const int lane = threadIdx.x & 63, w = threadIdx.x >> 6;
  if (lane == 0) { se[w] = e; sp[w] = p; }
  __syncthreads();
  if (threadIdx.x == 0) {
    atomicAdd(red + 0, se[0] + se[1] + se[2] + se[3]);
    atomicAdd(red + 1, sp[0] + sp[1] + sp[2] + sp[3]);
  }
}

__global__ void k_final(const float* __restrict__ red, float* __restrict__ out) {
  out[0] = logf(red[0]) - red[1];
}

extern "C" void kernel_launch(void* const* d_in, const int* in_sizes, int n_in,
                              void* d_out, int out_size, void* d_ws, size_t ws_size,
                              hipStream_t stream) {
  const float* feat = (const float*)d_in[0];
  const int*   src  = (const int*)d_in[1];
  const int*   dst  = (const int*)d_in[2];
  const int*   nsrc = (const int*)d_in[3];
  const int*   ndst = (const int*)d_in[4];
  const float* W    = (const float*)d_in[5];
  const float* b    = (const float*)d_in[6];
  const float* pa   = (const float*)d_in[7];
  const int nE  = in_sizes[1];
  const int nEn = in_sizes[3];
  float* out = (float*)d_out;

  float* m    = (float*)d_ws;
  float* aggP = m + (size_t)NTOT * DH;
  float* aggN = aggP + (size_t)NTOT * DH;
  float* degP = aggN + (size_t)NTOT * DH;
  float* degN = degP + NTOT;
  float* sims = degN + NTOT;
  float* red  = sims + 3 * NDST;

  // zero accumulators (aggP+aggN contiguous; degP..red contiguous)
  hipMemsetAsync(aggP, 0, 2 * (size_t)NTOT * DH * sizeof(float), stream);
  hipMemsetAsync(degP, 0, (2 * (size_t)NTOT + 3 * (size_t)NDST + 8) * sizeof(float), stream);

  k_gemm<<<NTOT / 64, 256, 0, stream>>>(feat, W, m);

  k_scatter<<<(nE + 3) / 4, 256, 0, stream>>>(m, src, dst, aggP, degP, nE);
  k_scatter<<<(nEn + 3) / 4, 256, 0, stream>>>(m, nsrc, ndst, aggN, degN, nEn);

  k_hnorm<true><<<NTOT, 256, 0, stream>>>(m, aggP, degP, b, pa, out + 1);
  k_hnorm<false><<<NTOT, 256, 0, stream>>>(m, aggN, degN, b, pa, nullptr);

  k_posloss<<<NDST / 4, 256, 0, stream>>>(aggP, aggN, sims);
  k_edgecos<<<(nEn + 3) / 4, 256, 0, stream>>>(aggP, aggN, nsrc, ndst, sims + NDST, nEn);
  k_edgecos<<<(nE + 3) / 4, 256, 0, stream>>>(aggN, aggP, src, dst, sims + 2 * NDST, nE);

  k_reduce<<<(3 * NDST) / 256, 256, 0, stream>>>(sims, red);
  k_final<<<1, 1, 0, stream>>>(red, out);
}

// Round 3
// 580.536 us; speedup vs baseline: 6.4522x; 6.4522x over previous
//
#include <hip/hip_runtime.h>
#include <math.h>

#define NSRC 32768
#define NTOT 65536
#define NDST 32768
#define DH   256

__device__ __forceinline__ float wave_reduce(float v) {
#pragma unroll
  for (int off = 32; off > 0; off >>= 1) v += __shfl_xor(v, off, 64);
  return v;
}

__device__ __forceinline__ float dot4(const float4& a, const float4& b) {
  return a.x * b.x + a.y * b.y + a.z * b.z + a.w * b.w;
}

// ---------------- GEMM: m[65536,256] = feat[65536,256] @ W[256,256] (f32) ----
__global__ __launch_bounds__(256) void k_gemm(const float* __restrict__ A,
                                              const float* __restrict__ B,
                                              float* __restrict__ C) {
  __shared__ float As[16][68];
  __shared__ float Bs[16][260];
  const int t  = threadIdx.x;
  const int bm = blockIdx.x * 64;
  const int tx = t & 15, ty = t >> 4;

  float acc[4][16];
#pragma unroll
  for (int i = 0; i < 4; ++i)
#pragma unroll
    for (int j = 0; j < 16; ++j) acc[i][j] = 0.f;

  const int arow = t >> 2;
  const int akq  = (t & 3) << 2;
  const int bk   = t >> 4;
  const int bn0  = (t & 15) << 4;

  for (int k0 = 0; k0 < 256; k0 += 16) {
    float4 av  = *(const float4*)(A + (size_t)(bm + arow) * 256 + k0 + akq);
    float4 bv0 = *(const float4*)(B + (size_t)(k0 + bk) * 256 + bn0);
    float4 bv1 = *(const float4*)(B + (size_t)(k0 + bk) * 256 + bn0 + 4);
    float4 bv2 = *(const float4*)(B + (size_t)(k0 + bk) * 256 + bn0 + 8);
    float4 bv3 = *(const float4*)(B + (size_t)(k0 + bk) * 256 + bn0 + 12);
    __syncthreads();
    As[akq + 0][arow] = av.x; As[akq + 1][arow] = av.y;
    As[akq + 2][arow] = av.z; As[akq + 3][arow] = av.w;
    *(float4*)&Bs[bk][bn0]      = bv0;
    *(float4*)&Bs[bk][bn0 + 4]  = bv1;
    *(float4*)&Bs[bk][bn0 + 8]  = bv2;
    *(float4*)&Bs[bk][bn0 + 12] = bv3;
    __syncthreads();
#pragma unroll
    for (int kk = 0; kk < 16; ++kk) {
      float4 a4 = *(const float4*)&As[kk][ty << 2];
      float ar[4] = {a4.x, a4.y, a4.z, a4.w};
#pragma unroll
      for (int q = 0; q < 4; ++q) {
        float4 b4 = *(const float4*)&Bs[kk][(tx << 4) + (q << 2)];
        float br[4] = {b4.x, b4.y, b4.z, b4.w};
#pragma unroll
        for (int i = 0; i < 4; ++i)
#pragma unroll
          for (int j = 0; j < 4; ++j)
            acc[i][(q << 2) + j] = fmaf(ar[i], br[j], acc[i][(q << 2) + j]);
      }
    }
  }
#pragma unroll
  for (int i = 0; i < 4; ++i)
#pragma unroll
    for (int q = 0; q < 4; ++q) {
      float4 o = {acc[i][4 * q], acc[i][4 * q + 1], acc[i][4 * q + 2], acc[i][4 * q + 3]};
      *(float4*)(C + (size_t)(bm + (ty << 2) + i) * 256 + (tx << 4) + (q << 2)) = o;
    }
}

// ---------------- CSR build --------------------------------------------------
__global__ __launch_bounds__(256) void k_deg(const int* __restrict__ dst,
                                             int* __restrict__ deg, int nE) {
  const int e = blockIdx.x * 256 + threadIdx.x;
  if (e < nE) atomicAdd(&deg[dst[e] - NSRC], 1);
}

// single block, 256 threads x 128 elems = 32768; exclusive scan -> rowStart
__global__ __launch_bounds__(256) void k_scan(const int* __restrict__ deg,
                                              int* __restrict__ rowStart) {
  __shared__ int tot[256];
  const int t = threadIdx.x;
  const int base = t * 128;
  int s = 0;
  for (int i = 0; i < 128; ++i) s += deg[base + i];
  tot[t] = s;
  __syncthreads();
  for (int off = 1; off < 256; off <<= 1) {
    int v = (t >= off) ? tot[t - off] : 0;
    __syncthreads();
    tot[t] += v;
    __syncthreads();
  }
  int pre = (t == 0) ? 0 : tot[t - 1];
  for (int i = 0; i < 128; ++i) {
    rowStart[base + i] = pre;
    pre += deg[base + i];
  }
  if (t == 255) rowStart[NDST] = pre;
}

__global__ __launch_bounds__(256) void k_fill(const int* __restrict__ src,
                                              const int* __restrict__ dst,
                                              const int* __restrict__ rowStart,
                                              int* __restrict__ cur,
                                              int* __restrict__ eSrc, int nE) {
  const int e = blockIdx.x * 256 + threadIdx.x;
  if (e >= nE) return;
  const int d = dst[e] - NSRC;
  const int p = atomicAdd(&cur[d], 1);
  eSrc[rowStart[d] + p] = src[e];
}

// ---------------- src-partition h (shared by both graphs), normalized -------
__global__ __launch_bounds__(256) void k_hsrc(const float* __restrict__ m,
                                              const float* __restrict__ b,
                                              const float* __restrict__ pa,
                                              float* __restrict__ hn) {
  const int row = blockIdx.x * 4 + (threadIdx.x >> 6);
  const int lane = threadIdx.x & 63;
  const size_t c = (size_t)lane * 4;
  float4 h = *(const float4*)(m + (size_t)row * DH + c);
  float4 bv = *(const float4*)(b + c);
  const float alpha = pa[0];
  h.x += bv.x; h.y += bv.y; h.z += bv.z; h.w += bv.w;
  h.x = h.x >= 0.f ? h.x : alpha * h.x;
  h.y = h.y >= 0.f ? h.y : alpha * h.y;
  h.z = h.z >= 0.f ? h.z : alpha * h.z;
  h.w = h.w >= 0.f ? h.w : alpha * h.w;
  float ss = wave_reduce(dot4(h, h));
  float inn = 1.0f / fmaxf(sqrtf(ss), 1e-8f);
  h.x *= inn; h.y *= inn; h.z *= inn; h.w *= inn;
  *(float4*)(hn + (size_t)row * DH + c) = h;
}

// ---------------- predict-partition aggregate + PReLU + normalize -----------
template <bool IS_POS>
__global__ __launch_bounds__(256) void k_agg(const float* __restrict__ m,
                                             const int* __restrict__ rowStart,
                                             const int* __restrict__ eSrc,
                                             const float* __restrict__ b,
                                             const float* __restrict__ pa,
                                             float* __restrict__ hraw,
                                             float* __restrict__ hn) {
  const int row = blockIdx.x * 4 + (threadIdx.x >> 6);
  const int lane = threadIdx.x & 63;
  const size_t c = (size_t)lane * 4;
  const int start = rowStart[row], end = rowStart[row + 1];
  float4 acc = *(const float4*)(m + (size_t)(NSRC + row) * DH + c);  // self-loop
  float4 acc2 = {0.f, 0.f, 0.f, 0.f};
  int e = start;
  for (; e + 1 < end; e += 2) {
    const int s0 = eSrc[e], s1 = eSrc[e + 1];
    float4 v0 = *(const float4*)(m + (size_t)s0 * DH + c);
    float4 v1 = *(const float4*)(m + (size_t)s1 * DH + c);
    acc.x += v0.x;  acc.y += v0.y;  acc.z += v0.z;  acc.w += v0.w;
    acc2.x += v1.x; acc2.y += v1.y; acc2.z += v1.z; acc2.w += v1.w;
  }
  if (e < end) {
    const int s = eSrc[e];
    float4 v = *(const float4*)(m + (size_t)s * DH + c);
    acc.x += v.x; acc.y += v.y; acc.z += v.z; acc.w += v.w;
  }
  acc.x += acc2.x; acc.y += acc2.y; acc.z += acc2.z; acc.w += acc2.w;
  const float inv = 1.0f / (float)(end - start + 1);
  float4 bv = *(const float4*)(b + c);
  const float alpha = pa[0];
  float4 h;
  h.x = acc.x * inv + bv.x; h.x = h.x >= 0.f ? h.x : alpha * h.x;
  h.y = acc.y * inv + bv.y; h.y = h.y >= 0.f ? h.y : alpha * h.y;
  h.z = acc.z * inv + bv.z; h.z = h.z >= 0.f ? h.z : alpha * h.z;
  h.w = acc.w * inv + bv.w; h.w = h.w >= 0.f ? h.w : alpha * h.w;
  if (IS_POS) *(float4*)(hraw + (size_t)row * DH + c) = h;
  float ss = wave_reduce(dot4(h, h));
  float inn = 1.0f / fmaxf(sqrtf(ss), 1e-8f);
  h.x *= inn; h.y *= inn; h.z *= inn; h.w *= inn;
  *(float4*)(hn + (size_t)row * DH + c) = h;
}

// ---------------- fused loss: pos + both neg halves, CSR-gather, no atomics -
__global__ __launch_bounds__(256) void k_loss(const float* __restrict__ hpd,
                                              const float* __restrict__ hnd,
                                              const float* __restrict__ hsrc,
                                              const int* __restrict__ rsP,
                                              const int* __restrict__ esP,
                                              const int* __restrict__ rsN,
                                              const int* __restrict__ esN,
                                              float* __restrict__ sims) {
  const int row = blockIdx.x * 4 + (threadIdx.x >> 6);
  const int lane = threadIdx.x & 63;
  const size_t c = (size_t)lane * 4;
  float4 xp = *(const float4*)(hpd + (size_t)row * DH + c);
  float4 xn = *(const float4*)(hnd + (size_t)row * DH + c);
  float posp = dot4(xp, xn);

  float a1 = 0.f, a1b = 0.f;
  {
    const int s0 = rsN[row], e0 = rsN[row + 1];
    int e = s0;
    for (; e + 1 < e0; e += 2) {
      float4 v0 = *(const float4*)(hsrc + (size_t)esN[e] * DH + c);
      float4 v1 = *(const float4*)(hsrc + (size_t)esN[e + 1] * DH + c);
      a1 += dot4(xp, v0);
      a1b += dot4(xp, v1);
    }
    if (e < e0) a1 += dot4(xp, *(const float4*)(hsrc + (size_t)esN[e] * DH + c));
  }
  float a2 = 0.f, a2b = 0.f;
  {
    const int s0 = rsP[row], e0 = rsP[row + 1];
    int e = s0;
    for (; e + 1 < e0; e += 2) {
      float4 v0 = *(const float4*)(hsrc + (size_t)esP[e] * DH + c);
      float4 v1 = *(const float4*)(hsrc + (size_t)esP[e + 1] * DH + c);
      a2 += dot4(xn, v0);
      a2b += dot4(xn, v1);
    }
    if (e < e0) a2 += dot4(xn, *(const float4*)(hsrc + (size_t)esP[e] * DH + c));
  }
  float pos = wave_reduce(posp);
  float n1 = wave_reduce(a1 + a1b);
  float n2 = wave_reduce(a2 + a2b);
  if (lane == 0) {
    sims[row] = pos;
    sims[NDST + row] = pos + n1;       // neg1 incl self-loop term
    sims[2 * NDST + row] = pos + n2;   // neg2 incl self-loop term
  }
}

// ---------------- final log-sum-exp reduce ----------------------------------
__global__ __launch_bounds__(256) void k_reduce(const float* __restrict__ sims,
                                                float* __restrict__ red) {
  const int i = blockIdx.x * 256 + threadIdx.x;  // 3*NDST = 384*256 exactly
  const float v = sims[i];
  float e = expf(v);
  float p = (i < NDST) ? v : 0.f;
  e = wave_reduce(e);
  p = wave_reduce(p);
  __shared__ float se[4], sp[4];
  const int lane = threadIdx.x & 63, w = threadIdx.x >> 6;
  if (lane == 0) { se[w] = e; sp[w] = p; }
  __syncthreads();
  if (threadIdx.x == 0) {
    atomicAdd(red + 0, se[0] + se[1] + se[2] + se[3]);
    atomicAdd(red + 1, sp[0] + sp[1] + sp[2] + sp[3]);
  }
}

__global__ void k_final(const float* __restrict__ red, float* __restrict__ out) {
  out[0] = logf(red[0]) - red[1];
}

extern "C" void kernel_launch(void* const* d_in, const int* in_sizes, int n_in,
                              void* d_out, int out_size, void* d_ws, size_t ws_size,
                              hipStream_t stream) {
  const float* feat = (const float*)d_in[0];
  const int*   src  = (const int*)d_in[1];
  const int*   dst  = (const int*)d_in[2];
  const int*   nsrc = (const int*)d_in[3];
  const int*   ndst = (const int*)d_in[4];
  const float* W    = (const float*)d_in[5];
  const float* b    = (const float*)d_in[6];
  const float* pa   = (const float*)d_in[7];
  const int nE  = in_sizes[1];
  const int nEn = in_sizes[3];
  float* out = (float*)d_out;

  float* m    = (float*)d_ws;                    // NTOT*DH
  float* hsrc = m + (size_t)NTOT * DH;           // NSRC*DH
  float* hpd  = hsrc + (size_t)NSRC * DH;        // NDST*DH
  float* hnd  = hpd + (size_t)NDST * DH;         // NDST*DH
  float* sims = hnd + (size_t)NDST * DH;         // 3*NDST
  float* red  = sims + 3 * (size_t)NDST;         // 8
  int* degP  = (int*)(red + 8);                  // NDST
  int* curP  = degP + NDST;                      // NDST
  int* degN  = curP + NDST;                      // NDST
  int* curN  = degN + NDST;                      // NDST
  int* rsP   = curN + NDST;                      // NDST+1
  int* rsN   = rsP + NDST + 1;                   // NDST+1
  int* eSrcP = rsN + NDST + 1;                   // nE
  int* eSrcN = eSrcP + nE;                       // nEn

  hipMemsetAsync(degP, 0, 4 * (size_t)NDST * sizeof(int), stream);
  hipMemsetAsync(red, 0, 8 * sizeof(float), stream);

  k_gemm<<<NTOT / 64, 256, 0, stream>>>(feat, W, m);

  k_deg<<<(nE + 255) / 256, 256, 0, stream>>>(dst, degP, nE);
  k_deg<<<(nEn + 255) / 256, 256, 0, stream>>>(ndst, degN, nEn);
  k_scan<<<1, 256, 0, stream>>>(degP, rsP);
  k_scan<<<1, 256, 0, stream>>>(degN, rsN);
  k_fill<<<(nE + 255) / 256, 256, 0, stream>>>(src, dst, rsP, curP, eSrcP, nE);
  k_fill<<<(nEn + 255) / 256, 256, 0, stream>>>(nsrc, ndst, rsN, curN, eSrcN, nEn);

  k_hsrc<<<NSRC / 4, 256, 0, stream>>>(m, b, pa, hsrc);
  k_agg<true><<<NDST / 4, 256, 0, stream>>>(m, rsP, eSrcP, b, pa, out + 1, hpd);
  k_agg<false><<<NDST / 4, 256, 0, stream>>>(m, rsN, eSrcN, b, pa, nullptr, hnd);

  k_loss<<<NDST / 4, 256, 0, stream>>>(hpd, hnd, hsrc, rsP, eSrcP, rsN, eSrcN, sims);

  k_reduce<<<(3 * NDST) / 256, 256, 0, stream>>>(sims, red);
  k_final<<<1, 1, 0, stream>>>(red, out);
}

// Round 4
// 396.786 us; speedup vs baseline: 9.4401x; 1.4631x over previous
//
#include <hip/hip_runtime.h>
#include <math.h>

#define NSRC 32768
#define NTOT 65536
#define NDST 32768
#define DH   256

typedef __attribute__((ext_vector_type(8))) short bf16x8;
typedef __attribute__((ext_vector_type(4))) float f32x4;

__device__ __forceinline__ float wave_reduce(float v) {
#pragma unroll
  for (int off = 32; off > 0; off >>= 1) v += __shfl_xor(v, off, 64);
  return v;
}
__device__ __forceinline__ unsigned short f2bf(float f) {
  union { float f; unsigned u; } v; v.f = f;
  unsigned r = v.u + 0x7FFFu + ((v.u >> 16) & 1u);
  return (unsigned short)(r >> 16);
}
__device__ __forceinline__ float bf2f(unsigned short h) {
  union { unsigned u; float f; } v; v.u = ((unsigned)h) << 16;
  return v.f;
}

// ---------------- W -> Wt (transpose + bf16) --------------------------------
__global__ __launch_bounds__(256) void k_cvtW(const float* __restrict__ W,
                                              unsigned short* __restrict__ Wt) {
  const int n = blockIdx.x, k = threadIdx.x;
  Wt[n * 256 + k] = f2bf(W[(size_t)k * 256 + n]);
}

// ---------------- MFMA GEMM: mb[row][n] = feat[row][:] @ W[:][n] (bf16 out) -
// Swapped operands: D' = Wt_frag (A-op) x featT_frag (B-op).
// Per wave: 16 rows (l&15), all 256 n. No LDS. Also emits hsrc for src rows.
__global__ __launch_bounds__(256) void k_gemm_mfma(
    const float* __restrict__ A, const unsigned short* __restrict__ Wt,
    const float* __restrict__ b, const float* __restrict__ pa,
    unsigned short* __restrict__ mb, unsigned short* __restrict__ hsrc) {
  const int t = threadIdx.x;
  const int lane = t & 63;
  const int wv = t >> 6;
  const int ln = lane & 15;
  const int kq = lane >> 4;          // 0..3
  const int row = blockIdx.x * 64 + wv * 16 + ln;

  // feat strip -> bf16 fragments (B-operand: B'[k][c]=feat[rowblk+c][k])
  bf16x8 bs[8];
  const float* ap = A + (size_t)row * 256 + kq * 8;
#pragma unroll
  for (int ks = 0; ks < 8; ++ks) {
    float4 a0 = *(const float4*)(ap + ks * 32);
    float4 a1 = *(const float4*)(ap + ks * 32 + 4);
    bf16x8 v;
    v[0] = (short)f2bf(a0.x); v[1] = (short)f2bf(a0.y);
    v[2] = (short)f2bf(a0.z); v[3] = (short)f2bf(a0.w);
    v[4] = (short)f2bf(a1.x); v[5] = (short)f2bf(a1.y);
    v[6] = (short)f2bf(a1.z); v[7] = (short)f2bf(a1.w);
    bs[ks] = v;
  }

  f32x4 acc[16];
#pragma unroll
  for (int i = 0; i < 16; ++i) acc[i] = (f32x4){0.f, 0.f, 0.f, 0.f};

#pragma unroll
  for (int nt = 0; nt < 16; ++nt) {
    const unsigned short* wp = Wt + (size_t)(nt * 16 + ln) * 256 + kq * 8;
#pragma unroll
    for (int ks = 0; ks < 8; ++ks) {
      bf16x8 af = *(const bf16x8*)(wp + ks * 32);
      acc[nt] = __builtin_amdgcn_mfma_f32_16x16x32_bf16(af, bs[ks], acc[nt], 0, 0, 0);
    }
  }

  // D'[r][c]: lane holds m[row][n], n = nt*16 + kq*4 + q  (4 consecutive n)
  const int n0 = kq * 4;
  const bool is_src = (row < NSRC);  // block-uniform (blockIdx < 512)
  const float alpha = pa[0];
  float ss = 0.f;
#pragma unroll
  for (int nt = 0; nt < 16; ++nt) {
    ushort4 o;
    o.x = f2bf(acc[nt][0]); o.y = f2bf(acc[nt][1]);
    o.z = f2bf(acc[nt][2]); o.w = f2bf(acc[nt][3]);
    *(ushort4*)(mb + (size_t)row * 256 + nt * 16 + n0) = o;
    if (is_src) {
      float4 bv = *(const float4*)(b + nt * 16 + n0);
      f32x4 h = acc[nt];
      h[0] += bv.x; h[1] += bv.y; h[2] += bv.z; h[3] += bv.w;
      h[0] = h[0] >= 0.f ? h[0] : alpha * h[0];
      h[1] = h[1] >= 0.f ? h[1] : alpha * h[1];
      h[2] = h[2] >= 0.f ? h[2] : alpha * h[2];
      h[3] = h[3] >= 0.f ? h[3] : alpha * h[3];
      acc[nt] = h;
      ss += h[0] * h[0] + h[1] * h[1] + h[2] * h[2] + h[3] * h[3];
    }
  }
  if (is_src) {
    ss += __shfl_xor(ss, 16, 64);
    ss += __shfl_xor(ss, 32, 64);
    float inn = 1.0f / fmaxf(sqrtf(ss), 1e-8f);
#pragma unroll
    for (int nt = 0; nt < 16; ++nt) {
      ushort4 o;
      o.x = f2bf(acc[nt][0] * inn); o.y = f2bf(acc[nt][1] * inn);
      o.z = f2bf(acc[nt][2] * inn); o.w = f2bf(acc[nt][3] * inn);
      *(ushort4*)(hsrc + (size_t)row * 256 + nt * 16 + n0) = o;
    }
  }
}

// ---------------- CSR build --------------------------------------------------
__global__ __launch_bounds__(256) void k_deg(const int* __restrict__ dst,
                                             int* __restrict__ deg, int nE) {
  const int e = blockIdx.x * 256 + threadIdx.x;
  if (e < nE) atomicAdd(&deg[dst[e] - NSRC], 1);
}

__global__ __launch_bounds__(256) void k_scan(const int* __restrict__ deg,
                                              int* __restrict__ rowStart) {
  __shared__ int tot[256];
  const int t = threadIdx.x;
  const int base = t * 128;
  int s = 0;
  for (int i = 0; i < 128; ++i) s += deg[base + i];
  tot[t] = s;
  __syncthreads();
  for (int off = 1; off < 256; off <<= 1) {
    int v = (t >= off) ? tot[t - off] : 0;
    __syncthreads();
    tot[t] += v;
    __syncthreads();
  }
  int pre = (t == 0) ? 0 : tot[t - 1];
  for (int i = 0; i < 128; ++i) {
    rowStart[base + i] = pre;
    pre += deg[base + i];
  }
  if (t == 255) rowStart[NDST] = pre;
}

__global__ __launch_bounds__(256) void k_fill(const int* __restrict__ src,
                                              const int* __restrict__ dst,
                                              const int* __restrict__ rowStart,
                                              int* __restrict__ cur,
                                              int* __restrict__ eSrc, int nE) {
  const int e = blockIdx.x * 256 + threadIdx.x;
  if (e >= nE) return;
  const int d = dst[e] - NSRC;
  const int p = atomicAdd(&cur[d], 1);
  eSrc[rowStart[d] + p] = src[e];
}

// ---------------- predict aggregate + PReLU + normalize (bf16 m) ------------
template <bool IS_POS>
__global__ __launch_bounds__(256) void k_agg(const unsigned short* __restrict__ mb,
                                             const int* __restrict__ rowStart,
                                             const int* __restrict__ eSrc,
                                             const float* __restrict__ b,
                                             const float* __restrict__ pa,
                                             float* __restrict__ hraw,
                                             unsigned short* __restrict__ hn) {
  const int row = blockIdx.x * 4 + (threadIdx.x >> 6);
  const int lane = threadIdx.x & 63;
  const int c = lane * 4;
  const int start = rowStart[row], end = rowStart[row + 1];
  ushort4 sv = *(const ushort4*)(mb + (size_t)(NSRC + row) * 256 + c);  // self
  float ax = bf2f(sv.x), ay = bf2f(sv.y), az = bf2f(sv.z), aw = bf2f(sv.w);
  float bx = 0.f, by = 0.f, bz = 0.f, bw = 0.f;
  int e = start;
  for (; e + 1 < end; e += 2) {
    ushort4 v0 = *(const ushort4*)(mb + (size_t)eSrc[e] * 256 + c);
    ushort4 v1 = *(const ushort4*)(mb + (size_t)eSrc[e + 1] * 256 + c);
    ax += bf2f(v0.x); ay += bf2f(v0.y); az += bf2f(v0.z); aw += bf2f(v0.w);
    bx += bf2f(v1.x); by += bf2f(v1.y); bz += bf2f(v1.z); bw += bf2f(v1.w);
  }
  if (e < end) {
    ushort4 v = *(const ushort4*)(mb + (size_t)eSrc[e] * 256 + c);
    ax += bf2f(v.x); ay += bf2f(v.y); az += bf2f(v.z); aw += bf2f(v.w);
  }
  ax += bx; ay += by; az += bz; aw += bw;
  const float inv = 1.0f / (float)(end - start + 1);
  float4 bv = *(const float4*)(b + c);
  const float alpha = pa[0];
  float hx = ax * inv + bv.x; hx = hx >= 0.f ? hx : alpha * hx;
  float hy = ay * inv + bv.y; hy = hy >= 0.f ? hy : alpha * hy;
  float hz = az * inv + bv.z; hz = hz >= 0.f ? hz : alpha * hz;
  float hw = aw * inv + bv.w; hw = hw >= 0.f ? hw : alpha * hw;
  if (IS_POS) {
    float4 o = {hx, hy, hz, hw};
    *(float4*)(hraw + (size_t)row * 256 + c) = o;
  }
  float ss = wave_reduce(hx * hx + hy * hy + hz * hz + hw * hw);
  float inn = 1.0f / fmaxf(sqrtf(ss), 1e-8f);
  ushort4 o;
  o.x = f2bf(hx * inn); o.y = f2bf(hy * inn);
  o.z = f2bf(hz * inn); o.w = f2bf(hw * inn);
  *(ushort4*)(hn + (size_t)row * 256 + c) = o;
}

// ---------------- fused loss (bf16 tables, CSR gathers, no atomics) ---------
__global__ __launch_bounds__(256) void k_loss(const unsigned short* __restrict__ hpd,
                                              const unsigned short* __restrict__ hnd,
                                              const unsigned short* __restrict__ hsrc,
                                              const int* __restrict__ rsP,
                                              const int* __restrict__ esP,
                                              const int* __restrict__ rsN,
                                              const int* __restrict__ esN,
                                              float* __restrict__ sims) {
  const int row = blockIdx.x * 4 + (threadIdx.x >> 6);
  const int lane = threadIdx.x & 63;
  const int c = lane * 4;
  ushort4 xpv = *(const ushort4*)(hpd + (size_t)row * 256 + c);
  ushort4 xnv = *(const ushort4*)(hnd + (size_t)row * 256 + c);
  const float px = bf2f(xpv.x), py = bf2f(xpv.y), pz = bf2f(xpv.z), pw = bf2f(xpv.w);
  const float nx = bf2f(xnv.x), ny = bf2f(xnv.y), nz = bf2f(xnv.z), nw = bf2f(xnv.w);
  float posp = px * nx + py * ny + pz * nz + pw * nw;

  float a1 = 0.f, a1b = 0.f;
  {
    const int s0 = rsN[row], e0 = rsN[row + 1];
    int e = s0;
    for (; e + 1 < e0; e += 2) {
      ushort4 v0 = *(const ushort4*)(hsrc + (size_t)esN[e] * 256 + c);
      ushort4 v1 = *(const ushort4*)(hsrc + (size_t)esN[e + 1] * 256 + c);
      a1 += px * bf2f(v0.x) + py * bf2f(v0.y) + pz * bf2f(v0.z) + pw * bf2f(v0.w);
      a1b += px * bf2f(v1.x) + py * bf2f(v1.y) + pz * bf2f(v1.z) + pw * bf2f(v1.w);
    }
    if (e < e0) {
      ushort4 v = *(const ushort4*)(hsrc + (size_t)esN[e] * 256 + c);
      a1 += px * bf2f(v.x) + py * bf2f(v.y) + pz * bf2f(v.z) + pw * bf2f(v.w);
    }
  }
  float a2 = 0.f, a2b = 0.f;
  {
    const int s0 = rsP[row], e0 = rsP[row + 1];
    int e = s0;
    for (; e + 1 < e0; e += 2) {
      ushort4 v0 = *(const ushort4*)(hsrc + (size_t)esP[e] * 256 + c);
      ushort4 v1 = *(const ushort4*)(hsrc + (size_t)esP[e + 1] * 256 + c);
      a2 += nx * bf2f(v0.x) + ny * bf2f(v0.y) + nz * bf2f(v0.z) + nw * bf2f(v0.w);
      a2b += nx * bf2f(v1.x) + ny * bf2f(v1.y) + nz * bf2f(v1.z) + nw * bf2f(v1.w);
    }
    if (e < e0) {
      ushort4 v = *(const ushort4*)(hsrc + (size_t)esP[e] * 256 + c);
      a2 += nx * bf2f(v.x) + ny * bf2f(v.y) + nz * bf2f(v.z) + nw * bf2f(v.w);
    }
  }
  float pos = wave_reduce(posp);
  float n1 = wave_reduce(a1 + a1b);
  float n2 = wave_reduce(a2 + a2b);
  if (lane == 0) {
    sims[row] = pos;
    sims[NDST + row] = pos + n1;
    sims[2 * NDST + row] = pos + n2;
  }
}

// ---------------- final log-sum-exp reduce ----------------------------------
__global__ __launch_bounds__(256) void k_reduce(const float* __restrict__ sims,
                                                float* __restrict__ red) {
  const int i = blockIdx.x * 256 + threadIdx.x;
  const float v = sims[i];
  float e = expf(v);
  float p = (i < NDST) ? v : 0.f;
  e = wave_reduce(e);
  p = wave_reduce(p);
  __shared__ float se[4], sp[4];
  const int lane = threadIdx.x & 63, w = threadIdx.x >> 6;
  if (lane == 0) { se[w] = e; sp[w] = p; }
  __syncthreads();
  if (threadIdx.x == 0) {
    atomicAdd(red + 0, se[0] + se[1] + se[2] + se[3]);
    atomicAdd(red + 1, sp[0] + sp[1] + sp[2] + sp[3]);
  }
}

__global__ void k_final(const float* __restrict__ red, float* __restrict__ out) {
  out[0] = logf(red[0]) - red[1];
}

extern "C" void kernel_launch(void* const* d_in, const int* in_sizes, int n_in,
                              void* d_out, int out_size, void* d_ws, size_t ws_size,
                              hipStream_t stream) {
  const float* feat = (const float*)d_in[0];
  const int*   src  = (const int*)d_in[1];
  const int*   dst  = (const int*)d_in[2];
  const int*   nsrc = (const int*)d_in[3];
  const int*   ndst = (const int*)d_in[4];
  const float* W    = (const float*)d_in[5];
  const float* b    = (const float*)d_in[6];
  const float* pa   = (const float*)d_in[7];
  const int nE  = in_sizes[1];
  const int nEn = in_sizes[3];
  float* out = (float*)d_out;

  unsigned short* mb   = (unsigned short*)d_ws;          // NTOT*256
  unsigned short* Wt   = mb + (size_t)NTOT * 256;        // 256*256
  unsigned short* hsrc = Wt + 256 * 256;                 // NSRC*256
  unsigned short* hpd  = hsrc + (size_t)NSRC * 256;      // NDST*256
  unsigned short* hnd  = hpd + (size_t)NDST * 256;       // NDST*256
  float* sims = (float*)(hnd + (size_t)NDST * 256);      // 3*NDST
  float* red  = sims + 3 * (size_t)NDST;                 // 8
  int* degP  = (int*)(red + 8);                          // NDST
  int* curP  = degP + NDST;
  int* degN  = curP + NDST;
  int* curN  = degN + NDST;
  int* rsP   = curN + NDST;                              // NDST+1
  int* rsN   = rsP + NDST + 1;                           // NDST+1
  int* eSrcP = rsN + NDST + 1;                           // nE
  int* eSrcN = eSrcP + nE;                               // nEn

  hipMemsetAsync(degP, 0, 4 * (size_t)NDST * sizeof(int), stream);
  hipMemsetAsync(red, 0, 8 * sizeof(float), stream);

  k_cvtW<<<256, 256, 0, stream>>>(W, Wt);
  k_gemm_mfma<<<NTOT / 64, 256, 0, stream>>>(feat, Wt, b, pa, mb, hsrc);

  k_deg<<<(nE + 255) / 256, 256, 0, stream>>>(dst, degP, nE);
  k_deg<<<(nEn + 255) / 256, 256, 0, stream>>>(ndst, degN, nEn);
  k_scan<<<1, 256, 0, stream>>>(degP, rsP);
  k_scan<<<1, 256, 0, stream>>>(degN, rsN);
  k_fill<<<(nE + 255) / 256, 256, 0, stream>>>(src, dst, rsP, curP, eSrcP, nE);
  k_fill<<<(nEn + 255) / 256, 256, 0, stream>>>(nsrc, ndst, rsN, curN, eSrcN, nEn);

  k_agg<true><<<NDST / 4, 256, 0, stream>>>(mb, rsP, eSrcP, b, pa, out + 1, hpd);
  k_agg<false><<<NDST / 4, 256, 0, stream>>>(mb, rsN, eSrcN, b, pa, nullptr, hnd);

  k_loss<<<NDST / 4, 256, 0, stream>>>(hpd, hnd, hsrc, rsP, eSrcP, rsN, eSrcN, sims);

  k_reduce<<<(3 * NDST) / 256, 256, 0, stream>>>(sims, red);
  k_final<<<1, 1, 0, stream>>>(red, out);
}